// Round 1
// baseline (130.914 us; speedup 1.0000x reference)
//
#include <hip/hip_runtime.h>
#include <hip/hip_bf16.h>
#include <math.h>

// ---------------------------------------------------------------------------
// PointerNet attention scorer, MI355X / gfx950.
//   sp' = 2*log2(e) * (src_enc @ W_src^T + b_src)   (B*S=4096, H=256)  [ws]
//   qp' = 2*log2(e) * (query   @ W_q^T   + b_q)     (T*B=2048, H=256)  [ws]
//   logit(t,b,s)  ~  -2 * sum_h w2[h] / (exp2(sp'+qp') + 1)   (shift-invariant
//   terms b2 + sum(w2) dropped; softmax is invariant to per-row shifts)
//   out = softmax_s(mask ? -inf : logit)
// ---------------------------------------------------------------------------

#define TANH_PRESCALE 2.8853900817779268f   // 2*log2(e)
#define LOG2E        1.4426950408889634f

__device__ __forceinline__ float fast_exp2(float x) {
#if __has_builtin(__builtin_amdgcn_exp2f)
    return __builtin_amdgcn_exp2f(x);
#else
    return exp2f(x);
#endif
}
__device__ __forceinline__ float fast_rcp(float x) {
#if __has_builtin(__builtin_amdgcn_rcpf)
    return __builtin_amdgcn_rcpf(x);
#else
    return 1.0f / x;
#endif
}

// ---------------------------------------------------------------------------
// Projection GEMM: C[m][n] = scale * (sum_k A[m][k] * W[n][k] + bias[n])
// K = 512 fixed, N = 256 fixed (ldc = 256). Tile 128m x 64n, 256 threads,
// 8x4 micro-tile. LDS tiles stored transposed [k][m] / [k][n] so fragment
// reads are ds_read_b128; leading dims padded (132 / 68) to keep the
// transpose stores at a tolerable 4-way bank conflict and reads conflict-free.
// z = 0: src projection (M0 rows), z = 1: query projection (M1 rows).
// ---------------------------------------------------------------------------
__global__ __launch_bounds__(256) void proj_gemm(
    const float* __restrict__ A0, const float* __restrict__ W0,
    const float* __restrict__ bias0, float* __restrict__ C0, int M0,
    const float* __restrict__ A1, const float* __restrict__ W1,
    const float* __restrict__ bias1, float* __restrict__ C1, int M1)
{
    const int z = blockIdx.z;
    const float* __restrict__ A    = z ? A1    : A0;
    const float* __restrict__ W    = z ? W1    : W0;
    const float* __restrict__ bias = z ? bias1 : bias0;
    float* __restrict__ C          = z ? C1    : C0;
    const int M = z ? M1 : M0;

    const int mb = blockIdx.x, nb = blockIdx.y;
    if (mb * 128 >= M) return;   // grid sized for the larger problem

    __shared__ float As[32][132];   // [k][m], pad 128 -> 132
    __shared__ float Ws[32][68];    // [k][n], pad 64  -> 68

    const int tid = threadIdx.x;
    const int kq  = tid & 7;     // k-quad 0..7 (covers 32 k as float4)
    const int rr  = tid >> 3;    // row 0..31
    const int mg  = tid >> 4;    // 0..15
    const int ng  = tid & 15;    // 0..15
    const int m0  = mg * 8, n0 = ng * 4;

    float acc[8][4];
    #pragma unroll
    for (int i = 0; i < 8; ++i)
        #pragma unroll
        for (int j = 0; j < 4; ++j) acc[i][j] = 0.0f;

    const float* Abase = A + ((size_t)mb * 128) * 512 + kq * 4;
    const float* Wbase = W + ((size_t)nb * 64)  * 512 + kq * 4;

    for (int kt = 0; kt < 512; kt += 32) {
        __syncthreads();   // previous compute done before overwriting LDS
        #pragma unroll
        for (int p = 0; p < 4; ++p) {           // A tile: 128 rows x 32 k
            const int row = rr + 32 * p;
            float4 v = *(const float4*)(Abase + (size_t)row * 512 + kt);
            As[kq * 4 + 0][row] = v.x;  As[kq * 4 + 1][row] = v.y;
            As[kq * 4 + 2][row] = v.z;  As[kq * 4 + 3][row] = v.w;
        }
        #pragma unroll
        for (int p = 0; p < 2; ++p) {           // W tile: 64 rows x 32 k
            const int n = rr + 32 * p;
            float4 v = *(const float4*)(Wbase + (size_t)n * 512 + kt);
            Ws[kq * 4 + 0][n] = v.x;  Ws[kq * 4 + 1][n] = v.y;
            Ws[kq * 4 + 2][n] = v.z;  Ws[kq * 4 + 3][n] = v.w;
        }
        __syncthreads();
        #pragma unroll
        for (int k = 0; k < 32; ++k) {
            float4 a0 = *(const float4*)&As[k][m0];
            float4 a1 = *(const float4*)&As[k][m0 + 4];
            float4 w  = *(const float4*)&Ws[k][n0];
            const float av[8] = {a0.x, a0.y, a0.z, a0.w, a1.x, a1.y, a1.z, a1.w};
            const float wv[4] = {w.x, w.y, w.z, w.w};
            #pragma unroll
            for (int i = 0; i < 8; ++i)
                #pragma unroll
                for (int j = 0; j < 4; ++j)
                    acc[i][j] = fmaf(av[i], wv[j], acc[i][j]);
        }
    }

    float4 bv = *(const float4*)(bias + nb * 64 + n0);
    const float bb[4] = {bv.x, bv.y, bv.z, bv.w};
    #pragma unroll
    for (int i = 0; i < 8; ++i) {
        float4 o;
        o.x = (acc[i][0] + bb[0]) * TANH_PRESCALE;
        o.y = (acc[i][1] + bb[1]) * TANH_PRESCALE;
        o.z = (acc[i][2] + bb[2]) * TANH_PRESCALE;
        o.w = (acc[i][3] + bb[3]) * TANH_PRESCALE;
        *(float4*)(C + (size_t)(mb * 128 + m0 + i) * 256 + nb * 64 + n0) = o;
    }
}

// ---------------------------------------------------------------------------
// Fused score + masked softmax.
// Block = 256 threads, one (b, 4-t chunk). qp'/w2 staged in LDS (broadcast
// reads, conflict-free); sp' streamed from global (L1/L2 resident: 4 MB
// total, each row reused 4x in-block). Thread owns (s, h-half) and carries
// 4 t-accumulators so qp/w2 LDS reads amortize over 4 elements.
// Then per-wave softmax over S=128 (wave w <-> t-local w).
// ---------------------------------------------------------------------------
__global__ __launch_bounds__(256) void attn_score(
    const float* __restrict__ sp, const float* __restrict__ qp,
    const float* __restrict__ w2, const int* __restrict__ mask,
    float* __restrict__ out)
{
    const int b  = blockIdx.x;   // 0..31
    const int tz = blockIdx.y;   // 0..15 (chunk of 4 t)
    const int tid = threadIdx.x;

    __shared__ float qp_s[4][256];
    __shared__ float w2_s[256];
    __shared__ float h2_s[2][4][128];

    {   // stage qp' (4 rows) and w2
        const int tl = tid >> 6, lane = tid & 63;
        const int t = tz * 4 + tl;
        float4 v = *(const float4*)(qp + (size_t)(t * 32 + b) * 256 + lane * 4);
        *(float4*)&qp_s[tl][lane * 4] = v;
        if (tid < 64) {
            float4 wv = *(const float4*)(w2 + tid * 4);
            *(float4*)&w2_s[tid * 4] = wv;
        }
    }
    __syncthreads();

    const int s    = tid & 127;
    const int half = tid >> 7;
    const int hb   = half * 128;
    const float* sprow = sp + (size_t)(b * 128 + s) * 256 + hb;

    float acc0 = 0.f, acc1 = 0.f, acc2 = 0.f, acc3 = 0.f;
    #pragma unroll 4
    for (int hq = 0; hq < 32; ++hq) {
        float4 s4 = *(const float4*)(sprow + hq * 4);
        float4 w4 = *(const float4*)&w2_s[hb + hq * 4];
        float4 q0 = *(const float4*)&qp_s[0][hb + hq * 4];
        float4 q1 = *(const float4*)&qp_s[1][hb + hq * 4];
        float4 q2 = *(const float4*)&qp_s[2][hb + hq * 4];
        float4 q3 = *(const float4*)&qp_s[3][hb + hq * 4];
        #define PN_TERM(sj, wj, q0j, q1j, q2j, q3j)                              \
            { float r;                                                           \
              r = fast_rcp(fast_exp2(sj + q0j) + 1.0f); acc0 = fmaf(wj, r, acc0);\
              r = fast_rcp(fast_exp2(sj + q1j) + 1.0f); acc1 = fmaf(wj, r, acc1);\
              r = fast_rcp(fast_exp2(sj + q2j) + 1.0f); acc2 = fmaf(wj, r, acc2);\
              r = fast_rcp(fast_exp2(sj + q3j) + 1.0f); acc3 = fmaf(wj, r, acc3); }
        PN_TERM(s4.x, w4.x, q0.x, q1.x, q2.x, q3.x)
        PN_TERM(s4.y, w4.y, q0.y, q1.y, q2.y, q3.y)
        PN_TERM(s4.z, w4.z, q0.z, q1.z, q2.z, q3.z)
        PN_TERM(s4.w, w4.w, q0.w, q1.w, q2.w, q3.w)
        #undef PN_TERM
    }
    h2_s[half][0][s] = acc0;
    h2_s[half][1][s] = acc1;
    h2_s[half][2][s] = acc2;
    h2_s[half][3][s] = acc3;
    __syncthreads();

    // softmax: wave wv handles t-local row wv; lane covers s and s+64
    const int wv = tid >> 6, lane = tid & 63;
    float v0 = -2.0f * (h2_s[0][wv][lane]      + h2_s[1][wv][lane]);
    float v1 = -2.0f * (h2_s[0][wv][lane + 64] + h2_s[1][wv][lane + 64]);
    if (mask[b * 128 + lane])      v0 = -__builtin_inff();
    if (mask[b * 128 + lane + 64]) v1 = -__builtin_inff();

    float mx = fmaxf(v0, v1);
    #pragma unroll
    for (int off = 32; off >= 1; off >>= 1) mx = fmaxf(mx, __shfl_xor(mx, off));
    float e0 = fast_exp2((v0 - mx) * LOG2E);   // -inf -> 0
    float e1 = fast_exp2((v1 - mx) * LOG2E);
    float sum = e0 + e1;
    #pragma unroll
    for (int off = 32; off >= 1; off >>= 1) sum += __shfl_xor(sum, off);
    const float r = fast_rcp(sum);

    const size_t ob = (size_t)((tz * 4 + wv) * 32 + b) * 128;
    out[ob + lane]      = e0 * r;
    out[ob + lane + 64] = e1 * r;
}

extern "C" void kernel_launch(void* const* d_in, const int* in_sizes, int n_in,
                              void* d_out, int out_size, void* d_ws, size_t ws_size,
                              hipStream_t stream) {
    const float* src   = (const float*)d_in[0];   // (B,S,E)   32*128*512
    const int*   mask  = (const int*)  d_in[1];   // (B,S)     bool -> int32
    const float* query = (const float*)d_in[2];   // (T,B,Q)   64*32*512
    const float* W_src = (const float*)d_in[3];   // (H,E)
    const float* b_src = (const float*)d_in[4];   // (H,)
    const float* W_q   = (const float*)d_in[5];   // (H,Q)
    const float* b_q   = (const float*)d_in[6];   // (H,)
    const float* w2    = (const float*)d_in[7];   // (H,)
    // d_in[8] = b2 : unused — softmax is invariant to per-row constant shift.
    float* out = (float*)d_out;

    float* sp = (float*)d_ws;            // 4096 x 256 fp32 = 4 MB
    float* qp = sp + 4096 * 256;         // 2048 x 256 fp32 = 2 MB

    dim3 gA(32, 4, 2);                   // z=0: src (M=4096), z=1: query (M=2048)
    proj_gemm<<<gA, 256, 0, stream>>>(src,   W_src, b_src, sp, 4096,
                                      query, W_q,   b_q,   qp, 2048);

    dim3 gB(32, 16);                     // (b, t-chunk of 4)
    attn_score<<<gB, 256, 0, stream>>>(sp, qp, w2, mask, out);
}

// Round 2
// 107.874 us; speedup vs baseline: 1.2136x; 1.2136x over previous
//
#include <hip/hip_runtime.h>
#include <hip/hip_bf16.h>
#include <math.h>

// ---------------------------------------------------------------------------
// PointerNet attention scorer, MI355X / gfx950.
//   sp' = 2*log2(e) * (src_enc @ W_src^T + b_src)  -> stored h-quad-interleaved
//         sp_q[h>>2][b*128+s][h&3]                  (coalesced float4 in attn)
//   qp' = 2*log2(e) * (query @ W_q^T + b_q)        -> row-major [t*32+b][h]
//   logit ~ -2 * sum_h w2[h] / (exp2(sp'+qp') + 1)  (shift-invariant terms
//   b2 + sum(w2) dropped; softmax invariant to per-row shifts)
//   out = softmax_s(mask ? -inf : logit)
// Projections run on MFMA (bf16 hi/lo 3-pass split: rel err ~2^-16).
// ---------------------------------------------------------------------------

#define TANH_PRESCALE 2.8853900817779268f   // 2*log2(e)
#define LOG2E        1.4426950408889634f

typedef __attribute__((ext_vector_type(8))) short short8;   // 8 bf16 = 4 VGPR
typedef __attribute__((ext_vector_type(4))) float f32x4;    // MFMA C/D frag

__device__ __forceinline__ float fast_exp2(float x) {
#if __has_builtin(__builtin_amdgcn_exp2f)
    return __builtin_amdgcn_exp2f(x);
#else
    return exp2f(x);
#endif
}
__device__ __forceinline__ float fast_rcp(float x) {
#if __has_builtin(__builtin_amdgcn_rcpf)
    return __builtin_amdgcn_rcpf(x);
#else
    return 1.0f / x;
#endif
}
__device__ __forceinline__ float hi_part(float x) {   // top-16-bit truncation (bf16 grid)
    return __uint_as_float(__float_as_uint(x) & 0xffff0000u);
}
// pack bf16(a)=low16, bf16(b)=high16 (truncating converts) in one v_perm
__device__ __forceinline__ unsigned pack2(float a, float b) {
    return __builtin_amdgcn_perm(__float_as_uint(b), __float_as_uint(a), 0x07060302u);
}

// ---------------------------------------------------------------------------
// MFMA projection GEMM: C = scale * (A @ W^T + bias); A (M,512), W (256,512).
// Tile 128m x 64n, 256 thr (4 waves), wave = 32m x 64n (2x4 16x16 frags).
// K-step 64; LDS holds bf16 hi/lo planes, pitch 72 (2-way bank alias = free).
// 3 MFMA passes per frag pair: hi*hi + hi*lo + lo*hi.
// z=0: store transposed h-quad-interleaved to C0 (cols = 4096). z=1: row-major.
// ---------------------------------------------------------------------------
#define APITCH 72
#define AHI 0
#define ALO (128 * APITCH)          // 9216
#define WHI (2 * 128 * APITCH)      // 18432
#define WLO (WHI + 64 * APITCH)     // 23040
#define LDS_USHORTS (WLO + 64 * APITCH)   // 27648 ushorts = 55.3 KB

__global__ __launch_bounds__(256) void proj_gemm(
    const float* __restrict__ A0, const float* __restrict__ W0,
    const float* __restrict__ bias0, float* __restrict__ C0, int M0,
    const float* __restrict__ A1, const float* __restrict__ W1,
    const float* __restrict__ bias1, float* __restrict__ C1, int M1)
{
    const int z = blockIdx.z;
    const float* __restrict__ A    = z ? A1    : A0;
    const float* __restrict__ W    = z ? W1    : W0;
    const float* __restrict__ bias = z ? bias1 : bias0;
    const int M = z ? M1 : M0;

    const int mb = blockIdx.x, nb = blockIdx.y;
    if (mb * 128 >= M) return;

    __shared__ unsigned short LdsU[LDS_USHORTS];

    const int tid  = threadIdx.x;
    const int lane = tid & 63;
    const int wv   = tid >> 6;        // wave 0..3 -> m offset wv*32
    const int kf4  = tid & 15;        // float4 index within 64-wide k tile
    const int rb   = tid >> 4;        // 0..15 staging row base
    const int l15  = lane & 15;
    const int q8   = (lane >> 4) * 8; // k sub-offset for fragments

    f32x4 acc[2][4];
    #pragma unroll
    for (int i = 0; i < 2; ++i)
        #pragma unroll
        for (int j = 0; j < 4; ++j) acc[i][j] = (f32x4){0.f, 0.f, 0.f, 0.f};

    const float* Ab = A + ((size_t)mb * 128) * 512 + kf4 * 4;
    const float* Wb = W + ((size_t)nb * 64)  * 512 + kf4 * 4;

    for (int kt = 0; kt < 512; kt += 64) {
        __syncthreads();
        #pragma unroll
        for (int p = 0; p < 8; ++p) {          // A: 128 rows x 64 k
            const int row = rb + 16 * p;
            float4 v = *(const float4*)(Ab + (size_t)row * 512 + kt);
            unsigned* dh = (unsigned*)&LdsU[AHI + row * APITCH + kf4 * 4];
            dh[0] = pack2(v.x, v.y);  dh[1] = pack2(v.z, v.w);
            float lx = v.x - hi_part(v.x), ly = v.y - hi_part(v.y);
            float lz = v.z - hi_part(v.z), lw = v.w - hi_part(v.w);
            unsigned* dl = (unsigned*)&LdsU[ALO + row * APITCH + kf4 * 4];
            dl[0] = pack2(lx, ly);    dl[1] = pack2(lz, lw);
        }
        #pragma unroll
        for (int p = 0; p < 4; ++p) {          // W: 64 rows x 64 k
            const int row = rb + 16 * p;
            float4 v = *(const float4*)(Wb + (size_t)row * 512 + kt);
            unsigned* dh = (unsigned*)&LdsU[WHI + row * APITCH + kf4 * 4];
            dh[0] = pack2(v.x, v.y);  dh[1] = pack2(v.z, v.w);
            float lx = v.x - hi_part(v.x), ly = v.y - hi_part(v.y);
            float lz = v.z - hi_part(v.z), lw = v.w - hi_part(v.w);
            unsigned* dl = (unsigned*)&LdsU[WLO + row * APITCH + kf4 * 4];
            dl[0] = pack2(lx, ly);    dl[1] = pack2(lz, lw);
        }
        __syncthreads();

        #pragma unroll
        for (int kk = 0; kk < 64; kk += 32) {
            short8 ah[2], al[2], wh[4], wl[4];
            #pragma unroll
            for (int mi = 0; mi < 2; ++mi) {
                const int row = wv * 32 + mi * 16 + l15;
                ah[mi] = *(const short8*)&LdsU[AHI + row * APITCH + kk + q8];
                al[mi] = *(const short8*)&LdsU[ALO + row * APITCH + kk + q8];
            }
            #pragma unroll
            for (int ni = 0; ni < 4; ++ni) {
                const int row = ni * 16 + l15;
                wh[ni] = *(const short8*)&LdsU[WHI + row * APITCH + kk + q8];
                wl[ni] = *(const short8*)&LdsU[WLO + row * APITCH + kk + q8];
            }
            #pragma unroll
            for (int mi = 0; mi < 2; ++mi)
                #pragma unroll
                for (int ni = 0; ni < 4; ++ni) {
                    acc[mi][ni] = __builtin_amdgcn_mfma_f32_16x16x32_bf16(
                        ah[mi], wh[ni], acc[mi][ni], 0, 0, 0);
                    acc[mi][ni] = __builtin_amdgcn_mfma_f32_16x16x32_bf16(
                        ah[mi], wl[ni], acc[mi][ni], 0, 0, 0);
                    acc[mi][ni] = __builtin_amdgcn_mfma_f32_16x16x32_bf16(
                        al[mi], wh[ni], acc[mi][ni], 0, 0, 0);
                }
        }
    }

    float bl[4];
    #pragma unroll
    for (int ni = 0; ni < 4; ++ni) bl[ni] = bias[nb * 64 + ni * 16 + l15];

    __syncthreads();
    if (z == 0) {
        // transpose via LDS, then store h-quad-interleaved:
        //   C0 float index = (nb*16 + nq)*16384 + (mb*128 + m)*4 + (n&3)
        float* E = (float*)LdsU;               // 128 x 68 (fits in 55 KB)
        #pragma unroll
        for (int mi = 0; mi < 2; ++mi)
            #pragma unroll
            for (int ni = 0; ni < 4; ++ni) {
                const int m = wv * 32 + mi * 16 + (lane >> 4) * 4;
                const int n = ni * 16 + l15;
                #pragma unroll
                for (int r = 0; r < 4; ++r)
                    E[(m + r) * 68 + n] = (acc[mi][ni][r] + bl[ni]) * TANH_PRESCALE;
            }
        __syncthreads();
        #pragma unroll
        for (int p = 0; p < 2; ++p) {
            const int nq = (tid >> 5) + 8 * p;        // 0..15
            #pragma unroll
            for (int j = 0; j < 4; ++j) {
                const int m = (tid & 31) + 32 * j;    // 0..127
                float4 vv = *(const float4*)&E[m * 68 + nq * 4];
                *(float4*)(C0 + ((size_t)(nb * 16 + nq)) * 16384
                              + (size_t)(mb * 128 + m) * 4) = vv;
            }
        }
    } else {
        #pragma unroll
        for (int mi = 0; mi < 2; ++mi)
            #pragma unroll
            for (int ni = 0; ni < 4; ++ni) {
                const int m = mb * 128 + wv * 32 + mi * 16 + (lane >> 4) * 4;
                const int n = nb * 64 + ni * 16 + l15;
                #pragma unroll
                for (int r = 0; r < 4; ++r)
                    C1[(size_t)(m + r) * 256 + n] = (acc[mi][ni][r] + bl[ni]) * TANH_PRESCALE;
            }
    }
}

// ---------------------------------------------------------------------------
// Fused score + masked softmax. Block = (b, 4-t chunk), 256 thr.
// sp_q reads are now float4, lane-coalesced (consecutive s -> consecutive
// 16B). qp'/w2 broadcast from LDS. Per-wave softmax over S=128.
// ---------------------------------------------------------------------------
__global__ __launch_bounds__(256) void attn_score(
    const float* __restrict__ spq, const float* __restrict__ qp,
    const float* __restrict__ w2, const int* __restrict__ mask,
    float* __restrict__ out)
{
    const int b  = blockIdx.x;   // 0..31
    const int tz = blockIdx.y;   // 0..15
    const int tid = threadIdx.x;

    __shared__ float qp_s[4][256];
    __shared__ float w2_s[256];
    __shared__ float h2_s[2][4][128];

    {
        const int tl = tid >> 6, lane = tid & 63;
        const int t = tz * 4 + tl;
        float4 v = *(const float4*)(qp + (size_t)(t * 32 + b) * 256 + lane * 4);
        *(float4*)&qp_s[tl][lane * 4] = v;
        if (tid < 64) {
            float4 wv = *(const float4*)(w2 + tid * 4);
            *(float4*)&w2_s[tid * 4] = wv;
        }
    }
    __syncthreads();

    const int s    = tid & 127;
    const int half = tid >> 7;
    const int hb   = half * 128;
    // h-quad-interleaved: float4 at hq_glob*16384 + (b*128+s)*4 holds h=4*hq..+3
    const float* sq = spq + (size_t)(half * 32) * 16384 + (size_t)(b * 128 + s) * 4;

    float acc0 = 0.f, acc1 = 0.f, acc2 = 0.f, acc3 = 0.f;
    #pragma unroll 4
    for (int hq = 0; hq < 32; ++hq) {
        float4 s4 = *(const float4*)(sq + (size_t)hq * 16384);
        float4 w4 = *(const float4*)&w2_s[hb + hq * 4];
        float4 q0 = *(const float4*)&qp_s[0][hb + hq * 4];
        float4 q1 = *(const float4*)&qp_s[1][hb + hq * 4];
        float4 q2 = *(const float4*)&qp_s[2][hb + hq * 4];
        float4 q3 = *(const float4*)&qp_s[3][hb + hq * 4];
        #define PN_TERM(sj, wj, q0j, q1j, q2j, q3j)                              \
            { float r;                                                           \
              r = fast_rcp(fast_exp2(sj + q0j) + 1.0f); acc0 = fmaf(wj, r, acc0);\
              r = fast_rcp(fast_exp2(sj + q1j) + 1.0f); acc1 = fmaf(wj, r, acc1);\
              r = fast_rcp(fast_exp2(sj + q2j) + 1.0f); acc2 = fmaf(wj, r, acc2);\
              r = fast_rcp(fast_exp2(sj + q3j) + 1.0f); acc3 = fmaf(wj, r, acc3); }
        PN_TERM(s4.x, w4.x, q0.x, q1.x, q2.x, q3.x)
        PN_TERM(s4.y, w4.y, q0.y, q1.y, q2.y, q3.y)
        PN_TERM(s4.z, w4.z, q0.z, q1.z, q2.z, q3.z)
        PN_TERM(s4.w, w4.w, q0.w, q1.w, q2.w, q3.w)
        #undef PN_TERM
    }
    h2_s[half][0][s] = acc0;
    h2_s[half][1][s] = acc1;
    h2_s[half][2][s] = acc2;
    h2_s[half][3][s] = acc3;
    __syncthreads();

    const int wv = tid >> 6, lane = tid & 63;
    float v0 = -2.0f * (h2_s[0][wv][lane]      + h2_s[1][wv][lane]);
    float v1 = -2.0f * (h2_s[0][wv][lane + 64] + h2_s[1][wv][lane + 64]);
    if (mask[b * 128 + lane])      v0 = -__builtin_inff();
    if (mask[b * 128 + lane + 64]) v1 = -__builtin_inff();

    float mx = fmaxf(v0, v1);
    #pragma unroll
    for (int off = 32; off >= 1; off >>= 1) mx = fmaxf(mx, __shfl_xor(mx, off));
    float e0 = fast_exp2((v0 - mx) * LOG2E);
    float e1 = fast_exp2((v1 - mx) * LOG2E);
    float sum = e0 + e1;
    #pragma unroll
    for (int off = 32; off >= 1; off >>= 1) sum += __shfl_xor(sum, off);
    const float r = fast_rcp(sum);

    const size_t ob = (size_t)((tz * 4 + wv) * 32 + b) * 128;
    out[ob + lane]      = e0 * r;
    out[ob + lane + 64] = e1 * r;
}

extern "C" void kernel_launch(void* const* d_in, const int* in_sizes, int n_in,
                              void* d_out, int out_size, void* d_ws, size_t ws_size,
                              hipStream_t stream) {
    const float* src   = (const float*)d_in[0];   // (B,S,E)
    const int*   mask  = (const int*)  d_in[1];   // (B,S)
    const float* query = (const float*)d_in[2];   // (T,B,Q)
    const float* W_src = (const float*)d_in[3];   // (H,E)
    const float* b_src = (const float*)d_in[4];
    const float* W_q   = (const float*)d_in[5];   // (H,Q)
    const float* b_q   = (const float*)d_in[6];
    const float* w2    = (const float*)d_in[7];
    // d_in[8] = b2 : unused (softmax shift-invariant)
    float* out = (float*)d_out;

    float* spq = (float*)d_ws;           // h-quad layout: 64*4096*4 f32 = 4 MB
    float* qp  = spq + 4096 * 256;       // row-major: 2048 x 256 f32 = 2 MB

    dim3 gA(32, 4, 2);                   // z=0: src (M=4096), z=1: query (M=2048)
    proj_gemm<<<gA, 256, 0, stream>>>(src,   W_src, b_src, spq, 4096,
                                      query, W_q,   b_q,   qp,  2048);

    dim3 gB(32, 16);
    attn_score<<<gB, 256, 0, stream>>>(spq, qp, w2, mask, out);
}